// Round 15
// baseline (223.500 us; speedup 1.0000x reference)
//
#include <hip/hip_runtime.h>
#include <hip/hip_bf16.h>

#define NN 50000
#define NE 500000
#define INDIM 128
#define NH 8
#define DH 32
#define HD 256
#define NPERM 100
#define NB_G 64
#define NC 10
#define SLOPE 0.2f
#define BCAP 64   // bucket capacity per node; Poisson(10) max over 50K nodes ~32, 2x margin

typedef short bf16x8 __attribute__((ext_vector_type(8)));
typedef float f32x4 __attribute__((ext_vector_type(4)));

__device__ inline float bf2f(unsigned short u) {
    union { unsigned int i; float f; } x; x.i = ((unsigned int)u) << 16; return x.f;
}
__device__ inline unsigned short f2bf(float f) {
    __hip_bfloat16 h = __float2bfloat16(f);
    return *reinterpret_cast<unsigned short*>(&h);
}

// ---------------- prep: zero counts + weight transpose + hg zero ----------------

#define NB_CNT ((NN + 255) / 256)   // 196

__global__ __launch_bounds__(256) void prep_kernel(
    int* __restrict__ counts,
    const float* __restrict__ W1, const float* __restrict__ W2,
    __hip_bfloat16* __restrict__ Wt1, __hip_bfloat16* __restrict__ Wt2,
    float* __restrict__ hg)
{
    int b = blockIdx.x;
    int c = threadIdx.x;
    if (b < NB_CNT) {
        int i = b * 256 + c;
        if (i < NN) counts[i] = 0;
    } else {
        int bb = b - NB_CNT;   // 0..383
        if (bb < INDIM) {
            Wt1[(size_t)c * INDIM + bb] = __float2bfloat16(W1[(size_t)bb * HD + c]);
        } else {
            int k = bb - INDIM;
            Wt2[(size_t)c * HD + k] = __float2bfloat16(W2[(size_t)k * HD + c]);
        }
        if (bb < NB_G) hg[bb * HD + c] = 0.f;
    }
}

// ---------------- MFMA GEMM (64 rows x 256 cols, 4 waves) + optional fused bucket scatter ----------------
// wave wc owns cols [wc*64, wc*64+64) = heads 2wc, 2wc+1; acc 4x4 fragments of 16x16.
// BK = 64. LDS K-loop: Xs[row][8 slots of 16B], physical slot p holds logical seg p^(row&7).
// bf16 path: global_load_lds, pre-swizzled global source; fp32 path: reg staging + swizzled ds_write.
// EPILOGUE: z restaged through LDS (16-row chunks) -> fully coalesced 16B global stores
//           (fixes R14's 2x write amplification from scalar 2B scattered stores).
// Blocks >= gemm_nblocks run the edge->bucket scatter instead (independent work, overlapped).

template<int IS_F32>
__global__ __launch_bounds__(256) void gemm_mfma_kernel(
    const void* __restrict__ Xv, const __hip_bfloat16* __restrict__ Wt,
    const float* __restrict__ al, const float* __restrict__ ar,
    __hip_bfloat16* __restrict__ zb, float* __restrict__ el, float* __restrict__ er,
    int nrows, int K, int gemm_nblocks,
    const int* __restrict__ dstv, const int* __restrict__ srcv,
    int* __restrict__ counts, int* __restrict__ bucket, int ne)
{
    __shared__ __attribute__((aligned(16))) unsigned short Xs[64 * 64];   // 8 KB (K-staging AND epilogue restage)
    int t = threadIdx.x;

    if ((int)blockIdx.x >= gemm_nblocks) {
        // fused bucket scatter (block-uniform branch, no barriers)
        int e = ((int)blockIdx.x - gemm_nblocks) * 256 + t;
        if (e < ne) {
            int d = dstv[e];
            int p = atomicAdd(&counts[d], 1);
            if (p < BCAP) bucket[(size_t)d * BCAP + p] = srcv[e];
        }
        return;
    }

    int l = t & 63;
    int wc = t >> 6;        // 0..3
    int nb = blockIdx.x * 64;
    int wcb = wc * 64;
    int lg = l >> 4;
    int lr = l & 15;

    const short* Wt16 = (const short*)Wt;

    f32x4 acc[4][4];
#pragma unroll
    for (int rb = 0; rb < 4; ++rb)
#pragma unroll
        for (int cf = 0; cf < 4; ++cf) acc[rb][cf] = (f32x4){0.f, 0.f, 0.f, 0.f};

    int srow = t >> 2;            // 0..63 (fp32 staging)
    int sslot = t & 3;
    int g_row0 = t >> 3;          // 0..31 (gload staging)
    int g_row1 = (t + 256) >> 3;  // 32..63
    int g_p    = t & 7;

    for (int kc = 0; kc < K; kc += 64) {
        bf16x8 b[2][4];
#pragma unroll
        for (int kh = 0; kh < 2; ++kh)
#pragma unroll
            for (int cf = 0; cf < 4; ++cf) {
                int col = wcb + cf * 16 + lr;
                b[kh][cf] = *(const bf16x8*)&Wt16[(size_t)col * K + kc + kh * 32 + lg * 8];
            }

        if (IS_F32) {
            bf16x8 xv0 = {0,0,0,0,0,0,0,0}, xv1 = {0,0,0,0,0,0,0,0};
            int gr = nb + srow;
            if (gr < nrows) {
                const float* Xf = (const float*)Xv;
                const float* p = &Xf[(size_t)gr * K + kc];
                float4 xa = *(const float4*)&p[sslot * 8];
                float4 xb = *(const float4*)&p[sslot * 8 + 4];
                float4 xc = *(const float4*)&p[(sslot + 4) * 8];
                float4 xd = *(const float4*)&p[(sslot + 4) * 8 + 4];
                xv0[0] = (short)f2bf(xa.x); xv0[1] = (short)f2bf(xa.y);
                xv0[2] = (short)f2bf(xa.z); xv0[3] = (short)f2bf(xa.w);
                xv0[4] = (short)f2bf(xb.x); xv0[5] = (short)f2bf(xb.y);
                xv0[6] = (short)f2bf(xb.z); xv0[7] = (short)f2bf(xb.w);
                xv1[0] = (short)f2bf(xc.x); xv1[1] = (short)f2bf(xc.y);
                xv1[2] = (short)f2bf(xc.z); xv1[3] = (short)f2bf(xc.w);
                xv1[4] = (short)f2bf(xd.x); xv1[5] = (short)f2bf(xd.y);
                xv1[6] = (short)f2bf(xd.z); xv1[7] = (short)f2bf(xd.w);
            }
            __syncthreads();
            *(bf16x8*)&Xs[srow * 64 + ((sslot ^ (srow & 7)) * 8)] = xv0;
            *(bf16x8*)&Xs[srow * 64 + (((sslot + 4) ^ (srow & 7)) * 8)] = xv1;
            __syncthreads();
        } else {
            const short* X16 = (const short*)Xv;
            __syncthreads();
            {
                int q0 = g_p ^ (g_row0 & 7);
                int q1 = g_p ^ (g_row1 & 7);
                const short* ga0 = &X16[(size_t)(nb + g_row0) * K + kc + q0 * 8];
                const short* ga1 = &X16[(size_t)(nb + g_row1) * K + kc + q1 * 8];
                __builtin_amdgcn_global_load_lds(
                    (const __attribute__((address_space(1))) void*)ga0,
                    (__attribute__((address_space(3))) void*)((char*)Xs + t * 16), 16, 0, 0);
                __builtin_amdgcn_global_load_lds(
                    (const __attribute__((address_space(1))) void*)ga1,
                    (__attribute__((address_space(3))) void*)((char*)Xs + (t + 256) * 16), 16, 0, 0);
            }
            __syncthreads();
        }

        bf16x8 a[2][4];
#pragma unroll
        for (int kh = 0; kh < 2; ++kh)
#pragma unroll
            for (int rb = 0; rb < 4; ++rb) {
                int row = rb * 16 + lr;
                int slot = (kh * 4 + lg) ^ (row & 7);
                a[kh][rb] = *(const bf16x8*)&Xs[row * 64 + slot * 8];
            }
#pragma unroll
        for (int kh = 0; kh < 2; ++kh)
#pragma unroll
            for (int rb = 0; rb < 4; ++rb)
#pragma unroll
                for (int cf = 0; cf < 4; ++cf)
                    acc[rb][cf] = __builtin_amdgcn_mfma_f32_16x16x32_bf16(a[kh][rb], b[kh][cf], acc[rb][cf], 0, 0, 0);
    }

    // ---- el/er epilogue (unchanged; uses acc registers) ----
    float al_c[4], ar_c[4];
#pragma unroll
    for (int cf = 0; cf < 4; ++cf) {
        al_c[cf] = al[wcb + cf * 16 + lr];
        ar_c[cf] = ar[wcb + cf * 16 + lr];
    }
#pragma unroll
    for (int rb = 0; rb < 4; ++rb) {
        int rbase = nb + rb * 16 + lg * 4;
        float p0[4], p1[4], q0[4], q1[4];
#pragma unroll
        for (int j = 0; j < 4; ++j) {
            p0[j] = acc[rb][0][j] * al_c[0] + acc[rb][1][j] * al_c[1];
            p1[j] = acc[rb][2][j] * al_c[2] + acc[rb][3][j] * al_c[3];
            q0[j] = acc[rb][0][j] * ar_c[0] + acc[rb][1][j] * ar_c[1];
            q1[j] = acc[rb][2][j] * ar_c[2] + acc[rb][3][j] * ar_c[3];
        }
#pragma unroll
        for (int m = 1; m < 16; m <<= 1) {
#pragma unroll
            for (int j = 0; j < 4; ++j) {
                p0[j] += __shfl_xor(p0[j], m);
                p1[j] += __shfl_xor(p1[j], m);
                q0[j] += __shfl_xor(q0[j], m);
                q1[j] += __shfl_xor(q1[j], m);
            }
        }
        if (lr == 0) {
#pragma unroll
            for (int j = 0; j < 4; ++j) {
                int r = rbase + j;
                if (r < nrows) {
                    el[(size_t)r * NH + 2 * wc]     = p0[j];
                    el[(size_t)r * NH + 2 * wc + 1] = p1[j];
                    er[(size_t)r * NH + 2 * wc]     = q0[j];
                    er[(size_t)r * NH + 2 * wc + 1] = q1[j];
                }
            }
        }
    }

    // ---- z epilogue: LDS restage (16 rows x 256 cols = 8 KB, reuses Xs) -> coalesced 16B stores ----
    unsigned short* zu = (unsigned short*)zb;
#pragma unroll
    for (int rb = 0; rb < 4; ++rb) {
        __syncthreads();   // K-loop ds_reads done (rb=0) / previous chunk readback done
        // fragment -> LDS: row_l = lg*4+j, col = wcb+cf*16+lr; short-index XOR swizzle
        // at 8-short (16B) granularity keeps readback chunks contiguous.
#pragma unroll
        for (int cf = 0; cf < 4; ++cf) {
#pragma unroll
            for (int j = 0; j < 4; ++j) {
                int row_l = lg * 4 + j;
                int col = wcb + cf * 16 + lr;
                Xs[row_l * 256 + (col ^ ((row_l & 7) << 3))] = f2bf(acc[rb][cf][j]);
            }
        }
        __syncthreads();
        // readback: 512 chunks of 8 shorts; thread t handles chunks t and t+256
#pragma unroll
        for (int cc = 0; cc < 2; ++cc) {
            int chunk = t + cc * 256;
            int row = chunk >> 5;          // 0..15
            int seg = chunk & 31;          // 0..31
            int gr = nb + rb * 16 + row;
            if (gr < nrows) {
                bf16x8 v = *(const bf16x8*)&Xs[row * 256 + ((seg ^ (row & 7)) * 8)];
                *(bf16x8*)&zu[(size_t)gr * HD + seg * 8] = v;
            }
        }
    }
}

// ---------------- per-dst-node attention aggregate (R9 structure = proven floor) ----------------

__global__ __launch_bounds__(256) void agg_kernel(
    const __hip_bfloat16* __restrict__ zb, const float* __restrict__ el, const float* __restrict__ er,
    const float* __restrict__ bias, const int* __restrict__ counts,
    const int* __restrict__ bucket, __hip_bfloat16* __restrict__ out, int nrows, int do_relu)
{
    int wid = (blockIdx.x * 256 + threadIdx.x) >> 6;
    int l = threadIdx.x & 63;
    if (wid >= nrows) return;   // wave-uniform
    int n = wid;
    int K = counts[n];
    if (K > BCAP) K = BCAP;
    const int* srcs = &bucket[(size_t)n * BCAP];
    const unsigned short* zu = (const unsigned short*)zb;

    int es = l >> 4;   // edge slot 0..3
    int li = l & 15;   // channel group: c0 = li*16
    int hh = li >> 1;  // head
    float ern = er[(size_t)n * NH + hh];
    int c0 = li * 16;

    float num[16];
#pragma unroll
    for (int j = 0; j < 16; ++j) num[j] = 0.f;
    float den = 0.f;

    for (int kb = 0; kb < K; kb += 4) {
        int k = kb + es;
        if (k < K) {
            int s = srcs[k];
            float v = el[(size_t)s * NH + hh] + ern;
            v = v > 0.f ? v : SLOPE * v;
            float w = __expf(v);
            den += w;
            const unsigned short* zr = &zu[(size_t)s * HD + c0];
            bf16x8 z0 = *(const bf16x8*)&zr[0];
            bf16x8 z1 = *(const bf16x8*)&zr[8];
#pragma unroll
            for (int j = 0; j < 8; ++j) {
                num[j]     += w * bf2f((unsigned short)z0[j]);
                num[8 + j] += w * bf2f((unsigned short)z1[j]);
            }
        }
    }

    den += __shfl_xor(den, 16);
    den += __shfl_xor(den, 32);
#pragma unroll
    for (int j = 0; j < 16; ++j) {
        num[j] += __shfl_xor(num[j], 16);
        num[j] += __shfl_xor(num[j], 32);
    }

    if (es == 0) {
        float inv = (K > 0) ? 1.0f / den : 0.f;   // deg-0 node -> out = bias
        unsigned short* op = (unsigned short*)out;
        float4 bva = *(const float4*)&bias[c0];
        float4 bvb = *(const float4*)&bias[c0 + 4];
        float4 bvc = *(const float4*)&bias[c0 + 8];
        float4 bvd = *(const float4*)&bias[c0 + 12];
        float bb[16] = {bva.x, bva.y, bva.z, bva.w, bvb.x, bvb.y, bvb.z, bvb.w,
                        bvc.x, bvc.y, bvc.z, bvc.w, bvd.x, bvd.y, bvd.z, bvd.w};
        bf16x8 o0, o1;
#pragma unroll
        for (int j = 0; j < 8; ++j) {
            float v0 = num[j] * inv + bb[j];
            float v1 = num[8 + j] * inv + bb[8 + j];
            if (do_relu) { v0 = fmaxf(v0, 0.f); v1 = fmaxf(v1, 0.f); }
            o0[j] = (short)f2bf(v0);
            o1[j] = (short)f2bf(v1);
        }
        *(bf16x8*)&op[(size_t)n * HD + c0] = o0;
        *(bf16x8*)&op[(size_t)n * HD + c0 + 8] = o1;
    }
}

// ---------------- readout ----------------

__global__ __launch_bounds__(256) void graph_sum_kernel(
    const __hip_bfloat16* __restrict__ h2, const int* __restrict__ gids,
    float* __restrict__ hg)
{
    int c = threadIdx.x;
    int n0 = blockIdx.x * 64;
    int n1 = n0 + 64;
    if (n0 >= NN) return;
    if (n1 > NN) n1 = NN;
    const unsigned short* hu = (const unsigned short*)h2;
    float acc = 0.f;
    int cur = gids[n0];
    for (int n = n0; n < n1; ++n) {
        int g = gids[n];
        if (g != cur) {
            atomicAdd(&hg[cur * HD + c], acc);
            acc = 0.f;
            cur = g;
        }
        acc += bf2f(hu[(size_t)n * HD + c]);
    }
    atomicAdd(&hg[cur * HD + c], acc);
}

__global__ void classifier_kernel(const float* __restrict__ hg, const float* __restrict__ perm,
                                  const float* __restrict__ Wc, const float* __restrict__ bc,
                                  const int* __restrict__ gids, float* __restrict__ out) {
    int g = blockIdx.x;
    int c = threadIdx.x;
    if (c >= NC) return;
    int lo = 0, hi = NN;
    while (lo < hi) { int mid = (lo + hi) >> 1; if (gids[mid] < g) lo = mid + 1; else hi = mid; }
    int s0 = lo;
    lo = 0; hi = NN;
    while (lo < hi) { int mid = (lo + hi) >> 1; if (gids[mid] < g + 1) lo = mid + 1; else hi = mid; }
    float cnt = fmaxf((float)(lo - s0), 1.0f);
    float inv = 1.0f / cnt;
    float sg = 0.f;
    for (int k = 0; k < HD; ++k) sg += hg[g * HD + k] * Wc[k * NC + c];
    float s = bc[c] + sg * inv;
    for (int k = 0; k < NPERM; ++k) s += perm[g * NPERM + k] * Wc[(HD + k) * NC + c];
    out[g * NC + c] = s;
}

// ---------------- launch ----------------

extern "C" void kernel_launch(void* const* d_in, const int* in_sizes, int n_in,
                              void* d_out, int out_size, void* d_ws, size_t ws_size,
                              hipStream_t stream) {
    const float* h    = (const float*)d_in[0];
    const float* perm = (const float*)d_in[1];
    const float* W1   = (const float*)d_in[2];
    const float* al1  = (const float*)d_in[3];
    const float* ar1  = (const float*)d_in[4];
    const float* b1   = (const float*)d_in[5];
    const float* W2   = (const float*)d_in[6];
    const float* al2  = (const float*)d_in[7];
    const float* ar2  = (const float*)d_in[8];
    const float* b2   = (const float*)d_in[9];
    const float* Wc   = (const float*)d_in[10];
    const float* bc   = (const float*)d_in[11];
    const int* src    = (const int*)d_in[12];
    const int* dst    = (const int*)d_in[13];
    const int* gids   = (const int*)d_in[14];
    float* out = (float*)d_out;

    __hip_bfloat16* zb  = (__hip_bfloat16*)d_ws;                  // N*256
    __hip_bfloat16* h1b = zb + (size_t)NN * HD;                   // N*256
    __hip_bfloat16* Wt1 = h1b + (size_t)NN * HD;                  // 256*128
    __hip_bfloat16* Wt2 = Wt1 + (size_t)HD * INDIM;               // 256*256
    float* el = (float*)(Wt2 + (size_t)HD * HD);                  // N*8
    float* er = el + (size_t)NN * NH;                             // N*8
    float* hg = er + (size_t)NN * NH;                             // B*256
    int* counts = (int*)(hg + NB_G * HD);                         // N
    int* bucket = counts + NN;                                    // N*BCAP (12.8 MB)

    int nblocks_e = (NE + 255) / 256;   // 1954 scatter blocks
    int gemm_blocks = (NN + 63) / 64;   // 782
    int wave_node_blocks = (NN * 64 + 255) / 256;

    // prep: zero counts + transpose weights + zero hg
    prep_kernel<<<NB_CNT + INDIM + HD, 256, 0, stream>>>(counts, W1, W2, Wt1, Wt2, hg);

    // layer-1 gemm with fused bucket scatter (independent work, overlapped)
    gemm_mfma_kernel<1><<<gemm_blocks + nblocks_e, 256, 0, stream>>>(
        h, Wt1, al1, ar1, zb, el, er, NN, INDIM,
        gemm_blocks, dst, src, counts, bucket, NE);
    agg_kernel<<<wave_node_blocks, 256, 0, stream>>>(zb, el, er, b1, counts, bucket, h1b, NN, 1);
    // layer 2 (bf16 input -> global_load_lds staging), no scatter
    gemm_mfma_kernel<0><<<gemm_blocks, 256, 0, stream>>>(
        h1b, Wt2, al2, ar2, zb, el, er, NN, HD,
        gemm_blocks, nullptr, nullptr, nullptr, nullptr, 0);
    agg_kernel<<<wave_node_blocks, 256, 0, stream>>>(zb, el, er, b2, counts, bucket, h1b, NN, 0);

    // readout
    graph_sum_kernel<<<(NN + 63) / 64, 256, 0, stream>>>(h1b, gids, hg);
    classifier_kernel<<<NB_G, 64, 0, stream>>>(hg, perm, Wc, bc, gids, out);
}

// Round 16
// 220.111 us; speedup vs baseline: 1.0154x; 1.0154x over previous
//
#include <hip/hip_runtime.h>
#include <hip/hip_bf16.h>

#define NN 50000
#define NE 500000
#define INDIM 128
#define NH 8
#define DH 32
#define HD 256
#define NPERM 100
#define NB_G 64
#define NC 10
#define SLOPE 0.2f
#define BCAP 64   // bucket capacity per node; Poisson(10) max over 50K nodes ~32, 2x margin

typedef short bf16x8 __attribute__((ext_vector_type(8)));
typedef float f32x4 __attribute__((ext_vector_type(4)));

__device__ inline float bf2f(unsigned short u) {
    union { unsigned int i; float f; } x; x.i = ((unsigned int)u) << 16; return x.f;
}
__device__ inline unsigned short f2bf(float f) {
    __hip_bfloat16 h = __float2bfloat16(f);
    return *reinterpret_cast<unsigned short*>(&h);
}

// ---------------- prep: zero counts + weight transpose + hg zero ----------------

#define NB_CNT ((NN + 255) / 256)   // 196

__global__ __launch_bounds__(256) void prep_kernel(
    int* __restrict__ counts,
    const float* __restrict__ W1, const float* __restrict__ W2,
    __hip_bfloat16* __restrict__ Wt1, __hip_bfloat16* __restrict__ Wt2,
    float* __restrict__ hg)
{
    int b = blockIdx.x;
    int c = threadIdx.x;
    if (b < NB_CNT) {
        int i = b * 256 + c;
        if (i < NN) counts[i] = 0;
    } else {
        int bb = b - NB_CNT;   // 0..383
        if (bb < INDIM) {
            Wt1[(size_t)c * INDIM + bb] = __float2bfloat16(W1[(size_t)bb * HD + c]);
        } else {
            int k = bb - INDIM;
            Wt2[(size_t)c * HD + k] = __float2bfloat16(W2[(size_t)k * HD + c]);
        }
        if (bb < NB_G) hg[bb * HD + c] = 0.f;
    }
}

// ---------------- MFMA GEMM (64 rows x 256 cols, 4 waves) + optional fused bucket scatter ----------------
// wave wc owns cols [wc*64, wc*64+64) = heads 2wc, 2wc+1; acc 4x4 fragments of 16x16.
// BK = 64. LDS K-loop: Xs[row][8 slots of 16B], physical slot p holds logical seg p^(row&7).
// bf16 path: global_load_lds, pre-swizzled global source; fp32 path: reg staging + swizzled ds_write.
// z: direct fragment stores (proven un-amplified, R14/R15 comparison).
// el/er: LDS-restaged then coalesced contiguous 4B stores (fixes R15's ~10x partial-line
//        write amplification: 4B writes from 4 lanes to 4 different 64B lines).
// Blocks >= gemm_nblocks run the edge->bucket scatter instead (independent work, overlapped).

template<int IS_F32>
__global__ __launch_bounds__(256) void gemm_mfma_kernel(
    const void* __restrict__ Xv, const __hip_bfloat16* __restrict__ Wt,
    const float* __restrict__ al, const float* __restrict__ ar,
    __hip_bfloat16* __restrict__ zb, float* __restrict__ el, float* __restrict__ er,
    int nrows, int K, int gemm_nblocks,
    const int* __restrict__ dstv, const int* __restrict__ srcv,
    int* __restrict__ counts, int* __restrict__ bucket, int ne)
{
    __shared__ __attribute__((aligned(16))) unsigned short Xs[64 * 64];   // 8 KB; reused as el/er stage (4 KB)
    int t = threadIdx.x;

    if ((int)blockIdx.x >= gemm_nblocks) {
        // fused bucket scatter (block-uniform branch, no barriers)
        int e = ((int)blockIdx.x - gemm_nblocks) * 256 + t;
        if (e < ne) {
            int d = dstv[e];
            int p = atomicAdd(&counts[d], 1);
            if (p < BCAP) bucket[(size_t)d * BCAP + p] = srcv[e];
        }
        return;
    }

    int l = t & 63;
    int wc = t >> 6;        // 0..3
    int nb = blockIdx.x * 64;
    int wcb = wc * 64;
    int lg = l >> 4;
    int lr = l & 15;

    const short* Wt16 = (const short*)Wt;

    f32x4 acc[4][4];
#pragma unroll
    for (int rb = 0; rb < 4; ++rb)
#pragma unroll
        for (int cf = 0; cf < 4; ++cf) acc[rb][cf] = (f32x4){0.f, 0.f, 0.f, 0.f};

    int srow = t >> 2;            // 0..63 (fp32 staging)
    int sslot = t & 3;
    int g_row0 = t >> 3;          // 0..31 (gload staging)
    int g_row1 = (t + 256) >> 3;  // 32..63
    int g_p    = t & 7;

    for (int kc = 0; kc < K; kc += 64) {
        bf16x8 b[2][4];
#pragma unroll
        for (int kh = 0; kh < 2; ++kh)
#pragma unroll
            for (int cf = 0; cf < 4; ++cf) {
                int col = wcb + cf * 16 + lr;
                b[kh][cf] = *(const bf16x8*)&Wt16[(size_t)col * K + kc + kh * 32 + lg * 8];
            }

        if (IS_F32) {
            bf16x8 xv0 = {0,0,0,0,0,0,0,0}, xv1 = {0,0,0,0,0,0,0,0};
            int gr = nb + srow;
            if (gr < nrows) {
                const float* Xf = (const float*)Xv;
                const float* p = &Xf[(size_t)gr * K + kc];
                float4 xa = *(const float4*)&p[sslot * 8];
                float4 xb = *(const float4*)&p[sslot * 8 + 4];
                float4 xc = *(const float4*)&p[(sslot + 4) * 8];
                float4 xd = *(const float4*)&p[(sslot + 4) * 8 + 4];
                xv0[0] = (short)f2bf(xa.x); xv0[1] = (short)f2bf(xa.y);
                xv0[2] = (short)f2bf(xa.z); xv0[3] = (short)f2bf(xa.w);
                xv0[4] = (short)f2bf(xb.x); xv0[5] = (short)f2bf(xb.y);
                xv0[6] = (short)f2bf(xb.z); xv0[7] = (short)f2bf(xb.w);
                xv1[0] = (short)f2bf(xc.x); xv1[1] = (short)f2bf(xc.y);
                xv1[2] = (short)f2bf(xc.z); xv1[3] = (short)f2bf(xc.w);
                xv1[4] = (short)f2bf(xd.x); xv1[5] = (short)f2bf(xd.y);
                xv1[6] = (short)f2bf(xd.z); xv1[7] = (short)f2bf(xd.w);
            }
            __syncthreads();
            *(bf16x8*)&Xs[srow * 64 + ((sslot ^ (srow & 7)) * 8)] = xv0;
            *(bf16x8*)&Xs[srow * 64 + (((sslot + 4) ^ (srow & 7)) * 8)] = xv1;
            __syncthreads();
        } else {
            const short* X16 = (const short*)Xv;
            __syncthreads();
            {
                int q0 = g_p ^ (g_row0 & 7);
                int q1 = g_p ^ (g_row1 & 7);
                const short* ga0 = &X16[(size_t)(nb + g_row0) * K + kc + q0 * 8];
                const short* ga1 = &X16[(size_t)(nb + g_row1) * K + kc + q1 * 8];
                __builtin_amdgcn_global_load_lds(
                    (const __attribute__((address_space(1))) void*)ga0,
                    (__attribute__((address_space(3))) void*)((char*)Xs + t * 16), 16, 0, 0);
                __builtin_amdgcn_global_load_lds(
                    (const __attribute__((address_space(1))) void*)ga1,
                    (__attribute__((address_space(3))) void*)((char*)Xs + (t + 256) * 16), 16, 0, 0);
            }
            __syncthreads();
        }

        bf16x8 a[2][4];
#pragma unroll
        for (int kh = 0; kh < 2; ++kh)
#pragma unroll
            for (int rb = 0; rb < 4; ++rb) {
                int row = rb * 16 + lr;
                int slot = (kh * 4 + lg) ^ (row & 7);
                a[kh][rb] = *(const bf16x8*)&Xs[row * 64 + slot * 8];
            }
#pragma unroll
        for (int kh = 0; kh < 2; ++kh)
#pragma unroll
            for (int rb = 0; rb < 4; ++rb)
#pragma unroll
                for (int cf = 0; cf < 4; ++cf)
                    acc[rb][cf] = __builtin_amdgcn_mfma_f32_16x16x32_bf16(a[kh][rb], b[kh][cf], acc[rb][cf], 0, 0, 0);
    }

    // ---- el/er partials -> LDS stage (reuse Xs as float buffer; 4 KB) ----
    float al_c[4], ar_c[4];
#pragma unroll
    for (int cf = 0; cf < 4; ++cf) {
        al_c[cf] = al[wcb + cf * 16 + lr];
        ar_c[cf] = ar[wcb + cf * 16 + lr];
    }

    __syncthreads();   // all waves finished K-loop ds_reads of Xs
    float* els = (float*)Xs;       // [512] = 64 rows x 8 heads
    float* ers = els + 512;

#pragma unroll
    for (int rb = 0; rb < 4; ++rb) {
        float p0[4], p1[4], q0[4], q1[4];
#pragma unroll
        for (int j = 0; j < 4; ++j) {
            p0[j] = acc[rb][0][j] * al_c[0] + acc[rb][1][j] * al_c[1];
            p1[j] = acc[rb][2][j] * al_c[2] + acc[rb][3][j] * al_c[3];
            q0[j] = acc[rb][0][j] * ar_c[0] + acc[rb][1][j] * ar_c[1];
            q1[j] = acc[rb][2][j] * ar_c[2] + acc[rb][3][j] * ar_c[3];
        }
#pragma unroll
        for (int m = 1; m < 16; m <<= 1) {
#pragma unroll
            for (int j = 0; j < 4; ++j) {
                p0[j] += __shfl_xor(p0[j], m);
                p1[j] += __shfl_xor(p1[j], m);
                q0[j] += __shfl_xor(q0[j], m);
                q1[j] += __shfl_xor(q1[j], m);
            }
        }
        if (lr == 0) {
#pragma unroll
            for (int j = 0; j < 4; ++j) {
                int row_l = rb * 16 + lg * 4 + j;
                els[row_l * 8 + 2 * wc]     = p0[j];
                els[row_l * 8 + 2 * wc + 1] = p1[j];
                ers[row_l * 8 + 2 * wc]     = q0[j];
                ers[row_l * 8 + 2 * wc + 1] = q1[j];
            }
        }
    }

    // ---- z epilogue: direct fragment stores (un-amplified; R14-proven) ----
    unsigned short* zu = (unsigned short*)zb;
#pragma unroll
    for (int rb = 0; rb < 4; ++rb) {
        int rbase = nb + rb * 16 + lg * 4;
#pragma unroll
        for (int j = 0; j < 4; ++j) {
            int r = rbase + j;
            if (r < nrows) {
#pragma unroll
                for (int cf = 0; cf < 4; ++cf)
                    zu[(size_t)r * HD + wcb + cf * 16 + lr] = f2bf(acc[rb][cf][j]);
            }
        }
    }

    __syncthreads();
    // ---- coalesced el/er writes: contiguous [nb*8, nb*8+512) float range ----
    int lim = (nrows - nb) * 8;
    if (lim > 512) lim = 512;
#pragma unroll
    for (int i = 0; i < 2; ++i) {
        int idx = t + i * 256;
        if (idx < lim) {
            el[(size_t)nb * 8 + idx] = els[idx];
            er[(size_t)nb * 8 + idx] = ers[idx];
        }
    }
}

// ---------------- per-dst-node attention aggregate (R9 structure = proven floor) ----------------

__global__ __launch_bounds__(256) void agg_kernel(
    const __hip_bfloat16* __restrict__ zb, const float* __restrict__ el, const float* __restrict__ er,
    const float* __restrict__ bias, const int* __restrict__ counts,
    const int* __restrict__ bucket, __hip_bfloat16* __restrict__ out, int nrows, int do_relu)
{
    int wid = (blockIdx.x * 256 + threadIdx.x) >> 6;
    int l = threadIdx.x & 63;
    if (wid >= nrows) return;   // wave-uniform
    int n = wid;
    int K = counts[n];
    if (K > BCAP) K = BCAP;
    const int* srcs = &bucket[(size_t)n * BCAP];
    const unsigned short* zu = (const unsigned short*)zb;

    int es = l >> 4;   // edge slot 0..3
    int li = l & 15;   // channel group: c0 = li*16
    int hh = li >> 1;  // head
    float ern = er[(size_t)n * NH + hh];
    int c0 = li * 16;

    float num[16];
#pragma unroll
    for (int j = 0; j < 16; ++j) num[j] = 0.f;
    float den = 0.f;

    for (int kb = 0; kb < K; kb += 4) {
        int k = kb + es;
        if (k < K) {
            int s = srcs[k];
            float v = el[(size_t)s * NH + hh] + ern;
            v = v > 0.f ? v : SLOPE * v;
            float w = __expf(v);
            den += w;
            const unsigned short* zr = &zu[(size_t)s * HD + c0];
            bf16x8 z0 = *(const bf16x8*)&zr[0];
            bf16x8 z1 = *(const bf16x8*)&zr[8];
#pragma unroll
            for (int j = 0; j < 8; ++j) {
                num[j]     += w * bf2f((unsigned short)z0[j]);
                num[8 + j] += w * bf2f((unsigned short)z1[j]);
            }
        }
    }

    den += __shfl_xor(den, 16);
    den += __shfl_xor(den, 32);
#pragma unroll
    for (int j = 0; j < 16; ++j) {
        num[j] += __shfl_xor(num[j], 16);
        num[j] += __shfl_xor(num[j], 32);
    }

    if (es == 0) {
        float inv = (K > 0) ? 1.0f / den : 0.f;   // deg-0 node -> out = bias
        unsigned short* op = (unsigned short*)out;
        float4 bva = *(const float4*)&bias[c0];
        float4 bvb = *(const float4*)&bias[c0 + 4];
        float4 bvc = *(const float4*)&bias[c0 + 8];
        float4 bvd = *(const float4*)&bias[c0 + 12];
        float bb[16] = {bva.x, bva.y, bva.z, bva.w, bvb.x, bvb.y, bvb.z, bvb.w,
                        bvc.x, bvc.y, bvc.z, bvc.w, bvd.x, bvd.y, bvd.z, bvd.w};
        bf16x8 o0, o1;
#pragma unroll
        for (int j = 0; j < 8; ++j) {
            float v0 = num[j] * inv + bb[j];
            float v1 = num[8 + j] * inv + bb[8 + j];
            if (do_relu) { v0 = fmaxf(v0, 0.f); v1 = fmaxf(v1, 0.f); }
            o0[j] = (short)f2bf(v0);
            o1[j] = (short)f2bf(v1);
        }
        *(bf16x8*)&op[(size_t)n * HD + c0] = o0;
        *(bf16x8*)&op[(size_t)n * HD + c0 + 8] = o1;
    }
}

// ---------------- readout ----------------

__global__ __launch_bounds__(256) void graph_sum_kernel(
    const __hip_bfloat16* __restrict__ h2, const int* __restrict__ gids,
    float* __restrict__ hg)
{
    int c = threadIdx.x;
    int n0 = blockIdx.x * 64;
    int n1 = n0 + 64;
    if (n0 >= NN) return;
    if (n1 > NN) n1 = NN;
    const unsigned short* hu = (const unsigned short*)h2;
    float acc = 0.f;
    int cur = gids[n0];
    for (int n = n0; n < n1; ++n) {
        int g = gids[n];
        if (g != cur) {
            atomicAdd(&hg[cur * HD + c], acc);
            acc = 0.f;
            cur = g;
        }
        acc += bf2f(hu[(size_t)n * HD + c]);
    }
    atomicAdd(&hg[cur * HD + c], acc);
}

__global__ void classifier_kernel(const float* __restrict__ hg, const float* __restrict__ perm,
                                  const float* __restrict__ Wc, const float* __restrict__ bc,
                                  const int* __restrict__ gids, float* __restrict__ out) {
    int g = blockIdx.x;
    int c = threadIdx.x;
    if (c >= NC) return;
    int lo = 0, hi = NN;
    while (lo < hi) { int mid = (lo + hi) >> 1; if (gids[mid] < g) lo = mid + 1; else hi = mid; }
    int s0 = lo;
    lo = 0; hi = NN;
    while (lo < hi) { int mid = (lo + hi) >> 1; if (gids[mid] < g + 1) lo = mid + 1; else hi = mid; }
    float cnt = fmaxf((float)(lo - s0), 1.0f);
    float inv = 1.0f / cnt;
    float sg = 0.f;
    for (int k = 0; k < HD; ++k) sg += hg[g * HD + k] * Wc[k * NC + c];
    float s = bc[c] + sg * inv;
    for (int k = 0; k < NPERM; ++k) s += perm[g * NPERM + k] * Wc[(HD + k) * NC + c];
    out[g * NC + c] = s;
}

// ---------------- launch ----------------

extern "C" void kernel_launch(void* const* d_in, const int* in_sizes, int n_in,
                              void* d_out, int out_size, void* d_ws, size_t ws_size,
                              hipStream_t stream) {
    const float* h    = (const float*)d_in[0];
    const float* perm = (const float*)d_in[1];
    const float* W1   = (const float*)d_in[2];
    const float* al1  = (const float*)d_in[3];
    const float* ar1  = (const float*)d_in[4];
    const float* b1   = (const float*)d_in[5];
    const float* W2   = (const float*)d_in[6];
    const float* al2  = (const float*)d_in[7];
    const float* ar2  = (const float*)d_in[8];
    const float* b2   = (const float*)d_in[9];
    const float* Wc   = (const float*)d_in[10];
    const float* bc   = (const float*)d_in[11];
    const int* src    = (const int*)d_in[12];
    const int* dst    = (const int*)d_in[13];
    const int* gids   = (const int*)d_in[14];
    float* out = (float*)d_out;

    __hip_bfloat16* zb  = (__hip_bfloat16*)d_ws;                  // N*256
    __hip_bfloat16* h1b = zb + (size_t)NN * HD;                   // N*256
    __hip_bfloat16* Wt1 = h1b + (size_t)NN * HD;                  // 256*128
    __hip_bfloat16* Wt2 = Wt1 + (size_t)HD * INDIM;               // 256*256
    float* el = (float*)(Wt2 + (size_t)HD * HD);                  // N*8
    float* er = el + (size_t)NN * NH;                             // N*8
    float* hg = er + (size_t)NN * NH;                             // B*256
    int* counts = (int*)(hg + NB_G * HD);                         // N
    int* bucket = counts + NN;                                    // N*BCAP (12.8 MB)

    int nblocks_e = (NE + 255) / 256;   // 1954 scatter blocks
    int gemm_blocks = (NN + 63) / 64;   // 782
    int wave_node_blocks = (NN * 64 + 255) / 256;

    // prep: zero counts + transpose weights + zero hg
    prep_kernel<<<NB_CNT + INDIM + HD, 256, 0, stream>>>(counts, W1, W2, Wt1, Wt2, hg);

    // layer-1 gemm with fused bucket scatter (independent work, overlapped)
    gemm_mfma_kernel<1><<<gemm_blocks + nblocks_e, 256, 0, stream>>>(
        h, Wt1, al1, ar1, zb, el, er, NN, INDIM,
        gemm_blocks, dst, src, counts, bucket, NE);
    agg_kernel<<<wave_node_blocks, 256, 0, stream>>>(zb, el, er, b1, counts, bucket, h1b, NN, 1);
    // layer 2 (bf16 input -> global_load_lds staging), no scatter
    gemm_mfma_kernel<0><<<gemm_blocks, 256, 0, stream>>>(
        h1b, Wt2, al2, ar2, zb, el, er, NN, HD,
        gemm_blocks, nullptr, nullptr, nullptr, nullptr, 0);
    agg_kernel<<<wave_node_blocks, 256, 0, stream>>>(zb, el, er, b2, counts, bucket, h1b, NN, 0);

    // readout
    graph_sum_kernel<<<(NN + 63) / 64, 256, 0, stream>>>(h1b, gids, hg);
    classifier_kernel<<<NB_G, 64, 0, stream>>>(hg, perm, Wc, bc, gids, out);
}

// Round 17
// 211.915 us; speedup vs baseline: 1.0547x; 1.0387x over previous
//
#include <hip/hip_runtime.h>
#include <hip/hip_bf16.h>

#define NN 50000
#define NE 500000
#define INDIM 128
#define NH 8
#define DH 32
#define HD 256
#define NPERM 100
#define NB_G 64
#define NC 10
#define SLOPE 0.2f
#define BCAP 64   // bucket capacity per node; Poisson(10) max over 50K nodes ~32, 2x margin

typedef short bf16x8 __attribute__((ext_vector_type(8)));
typedef float f32x4 __attribute__((ext_vector_type(4)));

__device__ inline float bf2f(unsigned short u) {
    union { unsigned int i; float f; } x; x.i = ((unsigned int)u) << 16; return x.f;
}
__device__ inline unsigned short f2bf(float f) {
    __hip_bfloat16 h = __float2bfloat16(f);
    return *reinterpret_cast<unsigned short*>(&h);
}

// ---------------- prep: zero counts + weight transpose + hg zero ----------------

#define NB_CNT ((NN + 255) / 256)   // 196

__global__ __launch_bounds__(256) void prep_kernel(
    int* __restrict__ counts,
    const float* __restrict__ W1, const float* __restrict__ W2,
    __hip_bfloat16* __restrict__ Wt1, __hip_bfloat16* __restrict__ Wt2,
    float* __restrict__ hg)
{
    int b = blockIdx.x;
    int c = threadIdx.x;
    if (b < NB_CNT) {
        int i = b * 256 + c;
        if (i < NN) counts[i] = 0;
    } else {
        int bb = b - NB_CNT;   // 0..383
        if (bb < INDIM) {
            Wt1[(size_t)c * INDIM + bb] = __float2bfloat16(W1[(size_t)bb * HD + c]);
        } else {
            int k = bb - INDIM;
            Wt2[(size_t)c * HD + k] = __float2bfloat16(W2[(size_t)k * HD + c]);
        }
        if (bb < NB_G) hg[bb * HD + c] = 0.f;
    }
}

// ---------------- MFMA GEMM, SINGLE-BARRIER: whole 64 x K X-panel staged at once ----------------
// R16 postmortem: per-K-iter barrier+vmcnt(0) drain with ~1.4 blocks/CU resident made the
// gemm latency-bound (MfmaUtil 2%, occ 17%). K=128/256 fits LDS whole (16/32 KB) -> stage the
// entire panel in one shot, ONE barrier, then an unrolled MFMA loop with zero further barriers.
// A from LDS (16B slots, phys slot p = logical q ^ (row&7): 2-way bank alias = free);
// B streamed per k-step from L2-resident Wt (no LDS, no barrier).
// z + el/er: direct stores (R14 form; R15/R16 proved restaging is a pure loss).
// Blocks >= gemm_nblocks run the edge->bucket scatter (independent, overlapped).

template<int KVAL, int IS_F32>
__global__ __launch_bounds__(256) void gemm_mfma_kernel(
    const void* __restrict__ Xv, const __hip_bfloat16* __restrict__ Wt,
    const float* __restrict__ al, const float* __restrict__ ar,
    __hip_bfloat16* __restrict__ zb, float* __restrict__ el, float* __restrict__ er,
    int nrows, int gemm_nblocks,
    const int* __restrict__ dstv, const int* __restrict__ srcv,
    int* __restrict__ counts, int* __restrict__ bucket, int ne)
{
    __shared__ __attribute__((aligned(16))) unsigned short Xs[64 * KVAL];   // 16/32 KB
    int t = threadIdx.x;

    if ((int)blockIdx.x >= gemm_nblocks) {
        // fused bucket scatter (block-uniform branch; never reaches the barrier)
        int e = ((int)blockIdx.x - gemm_nblocks) * 256 + t;
        if (e < ne) {
            int d = dstv[e];
            int p = atomicAdd(&counts[d], 1);
            if (p < BCAP) bucket[(size_t)d * BCAP + p] = srcv[e];
        }
        return;
    }

    int l = t & 63;
    int wc = t >> 6;        // 0..3
    int nb = blockIdx.x * 64;
    int wcb = wc * 64;
    int lg = l >> 4;
    int lr = l & 15;

    const short* Wt16 = (const short*)Wt;
    constexpr int NSLOT = KVAL / 8;       // 16B slots per row (16 or 32)
    constexpr int NKK = KVAL / 32;        // MFMA k-steps (4 or 8)

    // ---- stage entire X panel ----
    if (IS_F32) {
        // fp32 -> bf16 register staging: thread t owns row t>>2, slots (t&3)+4i
        const float* Xf = (const float*)Xv;
        int row = t >> 2;
        int gr = nb + row;
#pragma unroll
        for (int i = 0; i < NSLOT / 4; ++i) {
            int j = (t & 3) + 4 * i;
            bf16x8 xv = {0, 0, 0, 0, 0, 0, 0, 0};
            if (gr < nrows) {
                const float* p = &Xf[(size_t)gr * KVAL + j * 8];
                float4 xa = *(const float4*)&p[0];
                float4 xb = *(const float4*)&p[4];
                xv[0] = (short)f2bf(xa.x); xv[1] = (short)f2bf(xa.y);
                xv[2] = (short)f2bf(xa.z); xv[3] = (short)f2bf(xa.w);
                xv[4] = (short)f2bf(xb.x); xv[5] = (short)f2bf(xb.y);
                xv[6] = (short)f2bf(xb.z); xv[7] = (short)f2bf(xb.w);
            }
            *(bf16x8*)&Xs[row * KVAL + ((j ^ (row & 7)) * 8)] = xv;
        }
    } else {
        // bf16: global_load_lds, linear LDS dest, pre-swizzled global source
        const short* X16 = (const short*)Xv;
#pragma unroll
        for (int i = 0; i < (64 * NSLOT) / 256; ++i) {
            int c = t + i * 256;
            int row = c / NSLOT;
            int p = c % NSLOT;
            int q = p ^ (row & 7);
            const short* ga = &X16[(size_t)(nb + row) * KVAL + q * 8];
            __builtin_amdgcn_global_load_lds(
                (const __attribute__((address_space(1))) void*)ga,
                (__attribute__((address_space(3))) void*)((char*)Xs + (size_t)c * 16), 16, 0, 0);
        }
    }
    __syncthreads();   // THE single barrier

    // ---- MFMA loop, no barriers ----
    f32x4 acc[4][4];
#pragma unroll
    for (int rb = 0; rb < 4; ++rb)
#pragma unroll
        for (int cf = 0; cf < 4; ++cf) acc[rb][cf] = (f32x4){0.f, 0.f, 0.f, 0.f};

#pragma unroll
    for (int kk = 0; kk < NKK; ++kk) {
        bf16x8 b[4], a[4];
#pragma unroll
        for (int cf = 0; cf < 4; ++cf) {
            int col = wcb + cf * 16 + lr;
            b[cf] = *(const bf16x8*)&Wt16[(size_t)col * KVAL + kk * 32 + lg * 8];
        }
#pragma unroll
        for (int rb = 0; rb < 4; ++rb) {
            int row = rb * 16 + lr;
            int slot = (kk * 4 + lg) ^ (row & 7);
            a[rb] = *(const bf16x8*)&Xs[row * KVAL + slot * 8];
        }
#pragma unroll
        for (int rb = 0; rb < 4; ++rb)
#pragma unroll
            for (int cf = 0; cf < 4; ++cf)
                acc[rb][cf] = __builtin_amdgcn_mfma_f32_16x16x32_bf16(a[rb], b[cf], acc[rb][cf], 0, 0, 0);
    }

    // ---- epilogue: direct stores (R14 form) ----
    float al_c[4], ar_c[4];
#pragma unroll
    for (int cf = 0; cf < 4; ++cf) {
        al_c[cf] = al[wcb + cf * 16 + lr];
        ar_c[cf] = ar[wcb + cf * 16 + lr];
    }

    unsigned short* zu = (unsigned short*)zb;
#pragma unroll
    for (int rb = 0; rb < 4; ++rb) {
        int rbase = nb + rb * 16 + lg * 4;
#pragma unroll
        for (int j = 0; j < 4; ++j) {
            int r = rbase + j;
            if (r < nrows) {
#pragma unroll
                for (int cf = 0; cf < 4; ++cf)
                    zu[(size_t)r * HD + wcb + cf * 16 + lr] = f2bf(acc[rb][cf][j]);
            }
        }
        float p0[4], p1[4], q0[4], q1[4];
#pragma unroll
        for (int j = 0; j < 4; ++j) {
            p0[j] = acc[rb][0][j] * al_c[0] + acc[rb][1][j] * al_c[1];
            p1[j] = acc[rb][2][j] * al_c[2] + acc[rb][3][j] * al_c[3];
            q0[j] = acc[rb][0][j] * ar_c[0] + acc[rb][1][j] * ar_c[1];
            q1[j] = acc[rb][2][j] * ar_c[2] + acc[rb][3][j] * ar_c[3];
        }
#pragma unroll
        for (int m = 1; m < 16; m <<= 1) {
#pragma unroll
            for (int j = 0; j < 4; ++j) {
                p0[j] += __shfl_xor(p0[j], m);
                p1[j] += __shfl_xor(p1[j], m);
                q0[j] += __shfl_xor(q0[j], m);
                q1[j] += __shfl_xor(q1[j], m);
            }
        }
        if (lr == 0) {
#pragma unroll
            for (int j = 0; j < 4; ++j) {
                int r = rbase + j;
                if (r < nrows) {
                    el[(size_t)r * NH + 2 * wc]     = p0[j];
                    el[(size_t)r * NH + 2 * wc + 1] = p1[j];
                    er[(size_t)r * NH + 2 * wc]     = q0[j];
                    er[(size_t)r * NH + 2 * wc + 1] = q1[j];
                }
            }
        }
    }
}

// ---------------- per-dst-node attention aggregate (R9 structure = proven floor) ----------------

__global__ __launch_bounds__(256) void agg_kernel(
    const __hip_bfloat16* __restrict__ zb, const float* __restrict__ el, const float* __restrict__ er,
    const float* __restrict__ bias, const int* __restrict__ counts,
    const int* __restrict__ bucket, __hip_bfloat16* __restrict__ out, int nrows, int do_relu)
{
    int wid = (blockIdx.x * 256 + threadIdx.x) >> 6;
    int l = threadIdx.x & 63;
    if (wid >= nrows) return;   // wave-uniform
    int n = wid;
    int K = counts[n];
    if (K > BCAP) K = BCAP;
    const int* srcs = &bucket[(size_t)n * BCAP];
    const unsigned short* zu = (const unsigned short*)zb;

    int es = l >> 4;   // edge slot 0..3
    int li = l & 15;   // channel group: c0 = li*16
    int hh = li >> 1;  // head
    float ern = er[(size_t)n * NH + hh];
    int c0 = li * 16;

    float num[16];
#pragma unroll
    for (int j = 0; j < 16; ++j) num[j] = 0.f;
    float den = 0.f;

    for (int kb = 0; kb < K; kb += 4) {
        int k = kb + es;
        if (k < K) {
            int s = srcs[k];
            float v = el[(size_t)s * NH + hh] + ern;
            v = v > 0.f ? v : SLOPE * v;
            float w = __expf(v);
            den += w;
            const unsigned short* zr = &zu[(size_t)s * HD + c0];
            bf16x8 z0 = *(const bf16x8*)&zr[0];
            bf16x8 z1 = *(const bf16x8*)&zr[8];
#pragma unroll
            for (int j = 0; j < 8; ++j) {
                num[j]     += w * bf2f((unsigned short)z0[j]);
                num[8 + j] += w * bf2f((unsigned short)z1[j]);
            }
        }
    }

    den += __shfl_xor(den, 16);
    den += __shfl_xor(den, 32);
#pragma unroll
    for (int j = 0; j < 16; ++j) {
        num[j] += __shfl_xor(num[j], 16);
        num[j] += __shfl_xor(num[j], 32);
    }

    if (es == 0) {
        float inv = (K > 0) ? 1.0f / den : 0.f;   // deg-0 node -> out = bias
        unsigned short* op = (unsigned short*)out;
        float4 bva = *(const float4*)&bias[c0];
        float4 bvb = *(const float4*)&bias[c0 + 4];
        float4 bvc = *(const float4*)&bias[c0 + 8];
        float4 bvd = *(const float4*)&bias[c0 + 12];
        float bb[16] = {bva.x, bva.y, bva.z, bva.w, bvb.x, bvb.y, bvb.z, bvb.w,
                        bvc.x, bvc.y, bvc.z, bvc.w, bvd.x, bvd.y, bvd.z, bvd.w};
        bf16x8 o0, o1;
#pragma unroll
        for (int j = 0; j < 8; ++j) {
            float v0 = num[j] * inv + bb[j];
            float v1 = num[8 + j] * inv + bb[8 + j];
            if (do_relu) { v0 = fmaxf(v0, 0.f); v1 = fmaxf(v1, 0.f); }
            o0[j] = (short)f2bf(v0);
            o1[j] = (short)f2bf(v1);
        }
        *(bf16x8*)&op[(size_t)n * HD + c0] = o0;
        *(bf16x8*)&op[(size_t)n * HD + c0 + 8] = o1;
    }
}

// ---------------- readout ----------------

__global__ __launch_bounds__(256) void graph_sum_kernel(
    const __hip_bfloat16* __restrict__ h2, const int* __restrict__ gids,
    float* __restrict__ hg)
{
    int c = threadIdx.x;
    int n0 = blockIdx.x * 64;
    int n1 = n0 + 64;
    if (n0 >= NN) return;
    if (n1 > NN) n1 = NN;
    const unsigned short* hu = (const unsigned short*)h2;
    float acc = 0.f;
    int cur = gids[n0];
    for (int n = n0; n < n1; ++n) {
        int g = gids[n];
        if (g != cur) {
            atomicAdd(&hg[cur * HD + c], acc);
            acc = 0.f;
            cur = g;
        }
        acc += bf2f(hu[(size_t)n * HD + c]);
    }
    atomicAdd(&hg[cur * HD + c], acc);
}

__global__ void classifier_kernel(const float* __restrict__ hg, const float* __restrict__ perm,
                                  const float* __restrict__ Wc, const float* __restrict__ bc,
                                  const int* __restrict__ gids, float* __restrict__ out) {
    int g = blockIdx.x;
    int c = threadIdx.x;
    if (c >= NC) return;
    int lo = 0, hi = NN;
    while (lo < hi) { int mid = (lo + hi) >> 1; if (gids[mid] < g) lo = mid + 1; else hi = mid; }
    int s0 = lo;
    lo = 0; hi = NN;
    while (lo < hi) { int mid = (lo + hi) >> 1; if (gids[mid] < g + 1) lo = mid + 1; else hi = mid; }
    float cnt = fmaxf((float)(lo - s0), 1.0f);
    float inv = 1.0f / cnt;
    float sg = 0.f;
    for (int k = 0; k < HD; ++k) sg += hg[g * HD + k] * Wc[k * NC + c];
    float s = bc[c] + sg * inv;
    for (int k = 0; k < NPERM; ++k) s += perm[g * NPERM + k] * Wc[(HD + k) * NC + c];
    out[g * NC + c] = s;
}

// ---------------- launch ----------------

extern "C" void kernel_launch(void* const* d_in, const int* in_sizes, int n_in,
                              void* d_out, int out_size, void* d_ws, size_t ws_size,
                              hipStream_t stream) {
    const float* h    = (const float*)d_in[0];
    const float* perm = (const float*)d_in[1];
    const float* W1   = (const float*)d_in[2];
    const float* al1  = (const float*)d_in[3];
    const float* ar1  = (const float*)d_in[4];
    const float* b1   = (const float*)d_in[5];
    const float* W2   = (const float*)d_in[6];
    const float* al2  = (const float*)d_in[7];
    const float* ar2  = (const float*)d_in[8];
    const float* b2   = (const float*)d_in[9];
    const float* Wc   = (const float*)d_in[10];
    const float* bc   = (const float*)d_in[11];
    const int* src    = (const int*)d_in[12];
    const int* dst    = (const int*)d_in[13];
    const int* gids   = (const int*)d_in[14];
    float* out = (float*)d_out;

    __hip_bfloat16* zb  = (__hip_bfloat16*)d_ws;                  // N*256
    __hip_bfloat16* h1b = zb + (size_t)NN * HD;                   // N*256
    __hip_bfloat16* Wt1 = h1b + (size_t)NN * HD;                  // 256*128
    __hip_bfloat16* Wt2 = Wt1 + (size_t)HD * INDIM;               // 256*256
    float* el = (float*)(Wt2 + (size_t)HD * HD);                  // N*8
    float* er = el + (size_t)NN * NH;                             // N*8
    float* hg = er + (size_t)NN * NH;                             // B*256
    int* counts = (int*)(hg + NB_G * HD);                         // N
    int* bucket = counts + NN;                                    // N*BCAP (12.8 MB)

    int nblocks_e = (NE + 255) / 256;   // 1954 scatter blocks
    int gemm_blocks = (NN + 63) / 64;   // 782
    int wave_node_blocks = (NN * 64 + 255) / 256;

    // prep: zero counts + transpose weights + zero hg
    prep_kernel<<<NB_CNT + INDIM + HD, 256, 0, stream>>>(counts, W1, W2, Wt1, Wt2, hg);

    // layer-1 gemm (K=128, fp32 input) with fused bucket scatter
    gemm_mfma_kernel<INDIM, 1><<<gemm_blocks + nblocks_e, 256, 0, stream>>>(
        h, Wt1, al1, ar1, zb, el, er, NN,
        gemm_blocks, dst, src, counts, bucket, NE);
    agg_kernel<<<wave_node_blocks, 256, 0, stream>>>(zb, el, er, b1, counts, bucket, h1b, NN, 1);
    // layer 2 (K=256, bf16 input -> single-shot global_load_lds staging)
    gemm_mfma_kernel<HD, 0><<<gemm_blocks, 256, 0, stream>>>(
        h1b, Wt2, al2, ar2, zb, el, er, NN,
        gemm_blocks, nullptr, nullptr, nullptr, nullptr, 0);
    agg_kernel<<<wave_node_blocks, 256, 0, stream>>>(zb, el, er, b2, counts, bucket, h1b, NN, 0);

    // readout
    graph_sum_kernel<<<(NN + 63) / 64, 256, 0, stream>>>(h1b, gids, hg);
    classifier_kernel<<<NB_G, 64, 0, stream>>>(hg, perm, Wc, bc, gids, out);
}